// Round 15
// baseline (281.945 us; speedup 1.0000x reference)
//
#include <hip/hip_runtime.h>
#include <hip/hip_bf16.h>

#define N_ATOMS 30000
#define M_NBR   12

typedef __bf16 bf16x8 __attribute__((ext_vector_type(8)));
typedef float  f32x4  __attribute__((ext_vector_type(4)));

__device__ __forceinline__ unsigned pkbf(float a, float b) {
    union { __bf16 h[2]; unsigned u; } r;
    r.h[0] = (__bf16)a; r.h[1] = (__bf16)b;
    return r.u;
}
__device__ __forceinline__ unsigned short f2bf(float f) {
    union { __bf16 h; unsigned short s; } r; r.h = (__bf16)f; return r.s;
}
__device__ __forceinline__ float bflo(unsigned u) { union { unsigned x; float f; } v; v.x = u << 16;          return v.f; }
__device__ __forceinline__ float bfhi(unsigned u) { union { unsigned x; float f; } v; v.x = u & 0xffff0000u;  return v.f; }

__device__ __forceinline__ float fexp2(float x) { return __builtin_amdgcn_exp2f(x); }
__device__ __forceinline__ float flog2(float x) { return __builtin_amdgcn_logf(x); }

__device__ __forceinline__ float rowsum16(float x) {
    union { float f; int i; } a, b;
    a.f = x;
    b.i = __builtin_amdgcn_update_dpp(0, a.i, 0x121, 0xF, 0xF, true); a.f += b.f; // row_ror:1
    b.i = __builtin_amdgcn_update_dpp(0, a.i, 0x122, 0xF, 0xF, true); a.f += b.f; // row_ror:2
    b.i = __builtin_amdgcn_update_dpp(0, a.i, 0x124, 0xF, 0xF, true); a.f += b.f; // row_ror:4
    b.i = __builtin_amdgcn_update_dpp(0, a.i, 0x128, 0xF, 0xF, true); a.f += b.f; // row_ror:8
    return a.f;
}

// packed per-row address for z-column c (0..511): [band:8][l15:16][slot:4]
__device__ __forceinline__ int packAddr8(int c) {
    int cc = c & 255;
    int slot = ((cc >> 4) & 1) + ((c >> 8) << 1);
    return (cc >> 5) * 64 + (cc & 15) * 4 + slot;
}

// ---------------- Kernel 0: pack fc_w into bf16 fragment-order tables ----------
__global__ void pack_weights(const float* __restrict__ fc_w,
                             unsigned short* __restrict__ Wp1,
                             unsigned short* __restrict__ Wp3) {
    int idx = blockIdx.x * 256 + threadIdx.x;
    const int n1 = 32 * 1024 * 8;
    if (idx < n1) {
        int j = idx & 7, n = (idx >> 3) & 1023, g = idx >> 13;
        float v = (n < 512) ? fc_w[n * 640 + g * 8 + j]
                            : fc_w[(n - 512) * 640 + 256 + g * 8 + j];
        Wp1[idx] = f2bf(v);
    } else {
        int k = idx - n1;
        if (k < 16 * 512 * 8) {
            int j = k & 7, n = (k >> 3) & 511, g = k >> 12;
            Wp3[k] = f2bf(fc_w[n * 640 + 512 + g * 8 + j]);
        }
    }
}

// ---------------- Kernel 1: P1 = W1*atom + b, P2 = W2*atom, stored PACKED (bf16) ---
__global__ __launch_bounds__(512, 2) void gemm_p(
    const float* __restrict__ atom, const float* __restrict__ fc_b,
    const unsigned short* __restrict__ Wp1, unsigned short* __restrict__ P)
{
    __shared__ unsigned short sA[128 * 256];
    const int tid = threadIdx.x;
    const int r0 = blockIdx.x * 128;
    const int cb = blockIdx.y;

    #pragma unroll
    for (int s = 0; s < 8; ++s) {
        int G = tid + s * 512;
        int row = G >> 5, gc = G & 31;
        int grow = r0 + row;
        uint4 pk;
        if (grow < N_ATOMS) {
            const float4* src = reinterpret_cast<const float4*>(atom + (size_t)grow * 256 + gc * 8);
            float4 v0 = src[0], v1 = src[1];
            pk.x = pkbf(v0.x, v0.y); pk.y = pkbf(v0.z, v0.w);
            pk.z = pkbf(v1.x, v1.y); pk.w = pkbf(v1.z, v1.w);
        } else {
            pk = make_uint4(0u, 0u, 0u, 0u);
        }
        *reinterpret_cast<uint4*>(&sA[row * 256 + ((gc ^ (row & 7)) << 3)]) = pk;
    }
    __syncthreads();

    const int lane = tid & 63, wave = tid >> 6;
    const int wr = wave >> 2, wcc = wave & 3;
    const int l15 = lane & 15, l16 = lane >> 4;

    f32x4 acc[4][8];
    #pragma unroll
    for (int mt = 0; mt < 4; ++mt)
        #pragma unroll
        for (int nt = 0; nt < 8; ++nt) acc[mt][nt] = f32x4{0.f, 0.f, 0.f, 0.f};

    #pragma unroll
    for (int ks = 0; ks < 8; ++ks) {
        bf16x8 af[4];
        #pragma unroll
        for (int mt = 0; mt < 4; ++mt) {
            int row = wr * 64 + mt * 16 + l15;
            int g = ks * 4 + l16;
            af[mt] = *reinterpret_cast<const bf16x8*>(&sA[row * 256 + ((g ^ (row & 7)) << 3)]);
        }
        bf16x8 bfr[8];
        #pragma unroll
        for (int nt = 0; nt < 8; ++nt) {
            int col = cb * 512 + wcc * 128 + nt * 16 + l15;
            bfr[nt] = *reinterpret_cast<const bf16x8*>(&Wp1[((size_t)(ks * 4 + l16) * 1024 + col) * 8]);
        }
        #pragma unroll
        for (int mt = 0; mt < 4; ++mt)
            #pragma unroll
            for (int nt = 0; nt < 8; ++nt)
                acc[mt][nt] = __builtin_amdgcn_mfma_f32_16x16x32_bf16(af[mt], bfr[nt], acc[mt][nt], 0, 0, 0);
    }

    #pragma unroll
    for (int np = 0; np < 4; ++np) {
        int zc0 = wcc * 128 + np * 32 + l15;
        float b0 = (cb == 0) ? fc_b[zc0] : 0.f;
        float b1 = (cb == 0) ? fc_b[zc0 + 16] : 0.f;
        int pa = cb * 512 + packAddr8(zc0);
        #pragma unroll
        for (int mt = 0; mt < 4; ++mt) {
            #pragma unroll
            for (int j = 0; j < 4; ++j) {
                int row = r0 + wr * 64 + mt * 16 + l16 * 4 + j;
                if (row < N_ATOMS)
                    *reinterpret_cast<unsigned*>(&P[(size_t)row * 1024 + pa]) =
                        pkbf(acc[mt][2 * np][j] + b0, acc[mt][2 * np + 1][j] + b1);
            }
        }
    }
}

// ---------------- Kernel 2: 256 threads / 4 waves / ONE atom per block --------------
// 16 rows (12 real + 4 pad). Wave wc owns 64 gate + 64 core cols. acc[8] = 32 regs ->
// target 6 waves/SIMD (6 blocks/CU = 6 independent barrier streams).
// nt = p*4 + np*2 + b ; col = p*256 + wc*64 + np*32 + b*16 + l15.
__global__ __launch_bounds__(256, 6) void fused_conv(
    const float* __restrict__ atom, const float* __restrict__ bond,
    const int* __restrict__ nbr, const unsigned short* __restrict__ P,
    const unsigned short* __restrict__ Wp3,
    const float* __restrict__ ln1_g, const float* __restrict__ ln1_b,
    const float* __restrict__ ln2_g, const float* __restrict__ ln2_b,
    float* __restrict__ out)
{
    __shared__ unsigned short sA[16 * 128];             // 4KB bond tile (bf16, swizzled)
    __shared__ __align__(16) float sRed[2][16][4];      // LN1 wave partials
    __shared__ __align__(16) float sL2[2][4];           // [s|q][wave] LN2 partials

    const int tid = threadIdx.x;
    const int gi = blockIdx.x;                          // 30000 blocks, one atom each
    const int lane = tid & 63, wc = tid >> 6;
    const int l15 = lane & 15, l16 = lane >> 4;
    const float L2E = 1.4426950408889634f;
    const char* Pb = reinterpret_cast<const char*>(P);
    const unsigned cOffA = (unsigned)(wc * 256 + l15 * 8);   // band 2wc
    const unsigned cOffB = cOffA + 128u;                     // band 2wc+1

    // ---- 1) bond loads: 384 granules (12 rows x 32 x 4 floats) ----
    float4 bv0, bv1;
    {
        int row = tid >> 5, gc = tid & 31;
        bv0 = *reinterpret_cast<const float4*>(bond + (size_t)(gi * 12 + row) * 128 + gc * 4);
    }
    if (tid < 128) {
        int g2 = tid + 256;
        int r2 = g2 >> 5, c2 = g2 & 31;
        bv1 = *reinterpret_cast<const float4*>(bond + (size_t)(gi * 12 + r2) * 128 + c2 * 4);
    }

    // ---- 2) nbr + P2/P1 gathers (rows l16*4+j; l16==3 rows are pads, clamp nbr) ----
    int off = (l16 < 3) ? (l16 * 4) : 8;
    int4 nbq = *reinterpret_cast<const int4*>(&nbr[gi * 12 + off]);
    uint2 p2q[4][2];
    {
        const int* nn = reinterpret_cast<const int*>(&nbq);
        #pragma unroll
        for (int j = 0; j < 4; ++j) {
            unsigned b = (unsigned)nn[j] * 2048u + 1024u;
            p2q[j][0] = *reinterpret_cast<const uint2*>(Pb + b + cOffA);
            p2q[j][1] = *reinterpret_cast<const uint2*>(Pb + b + cOffB);
        }
    }
    uint2 p1qA = *reinterpret_cast<const uint2*>(Pb + (unsigned)gi * 2048u + cOffA);
    uint2 p1qB = *reinterpret_cast<const uint2*>(Pb + (unsigned)gi * 2048u + cOffB);

    // ---- 3) stage bond -> LDS (waits bond only); zero pad rows 12..15 ----
    {
        int row = tid >> 5, gc = tid & 31;
        uint2 pk;
        pk.x = pkbf(bv0.x, bv0.y); pk.y = pkbf(bv0.z, bv0.w);
        int elem = (((gc >> 1) ^ (row & 7)) << 3) + ((gc & 1) << 2);
        *reinterpret_cast<uint2*>(&sA[row * 128 + elem]) = pk;
    }
    if (tid < 128) {
        int g2 = tid + 256;
        int r2 = g2 >> 5, c2 = g2 & 31;
        uint2 pk2;
        pk2.x = pkbf(bv1.x, bv1.y); pk2.y = pkbf(bv1.z, bv1.w);
        int e2 = (((c2 >> 1) ^ (r2 & 7)) << 3) + ((c2 & 1) << 2);
        *reinterpret_cast<uint2*>(&sA[r2 * 128 + e2]) = pk2;
    }
    *reinterpret_cast<unsigned*>(&sA[1536 + tid * 2]) = 0u;   // rows 12..15

    // ---- 4) acc := P1 + P2 (gather regs die before GEMM) ----
    f32x4 acc[8];
    {
        float pg0 = bflo(p1qA.x), pg1 = bfhi(p1qA.x);
        float pc0 = bflo(p1qA.y), pc1 = bfhi(p1qA.y);
        float qg0 = bflo(p1qB.x), qg1 = bfhi(p1qB.x);
        float qc0 = bflo(p1qB.y), qc1 = bfhi(p1qB.y);
        #pragma unroll
        for (int j = 0; j < 4; ++j) {
            uint2 cA = p2q[j][0], cB = p2q[j][1];
            acc[0][j] = pg0 + bflo(cA.x); acc[1][j] = pg1 + bfhi(cA.x);
            acc[4][j] = pc0 + bflo(cA.y); acc[5][j] = pc1 + bfhi(cA.y);
            acc[2][j] = qg0 + bflo(cB.x); acc[3][j] = qg1 + bfhi(cB.x);
            acc[6][j] = qc0 + bflo(cB.y); acc[7][j] = qc1 + bfhi(cB.y);
        }
    }
    __syncthreads();                                    // B1: sA ready

    // ---- GEMM: acc += [16,128(bond)] @ Wp3 ----
    #pragma unroll
    for (int ks = 0; ks < 4; ++ks) {
        int row = l15;
        bf16x8 af = *reinterpret_cast<const bf16x8*>(
            &sA[row * 128 + (((ks * 4 + l16) ^ (row & 7)) << 3)]);
        #pragma unroll
        for (int p = 0; p < 2; ++p)
            #pragma unroll
            for (int np = 0; np < 2; ++np) {
                int colbase = p * 256 + wc * 64 + np * 32 + l15;
                bf16x8 b0 = *reinterpret_cast<const bf16x8*>(
                    &Wp3[((size_t)(ks * 4 + l16) * 512 + colbase) * 8]);
                bf16x8 b1 = *reinterpret_cast<const bf16x8*>(
                    &Wp3[((size_t)(ks * 4 + l16) * 512 + colbase + 16) * 8]);
                acc[p * 4 + np * 2 + 0] = __builtin_amdgcn_mfma_f32_16x16x32_bf16(
                    af, b0, acc[p * 4 + np * 2 + 0], 0, 0, 0);
                acc[p * 4 + np * 2 + 1] = __builtin_amdgcn_mfma_f32_16x16x32_bf16(
                    af, b1, acc[p * 4 + np * 2 + 1], 0, 0, 0);
            }
    }

    // ---- pass 1: LN1 partial stats per row (pad rows produce unused values) ----
    #pragma unroll
    for (int j = 0; j < 4; ++j) {
        int row = l16 * 4 + j;
        float s = 0.f, q = 0.f;
        #pragma unroll
        for (int nt = 0; nt < 8; ++nt) {
            float z = acc[nt][j];
            s += z; q = fmaf(z, z, q);
        }
        s = rowsum16(s);
        q = rowsum16(q);
        if (l15 == 0) { sRed[0][row][wc] = s; sRed[1][row][wc] = q; }
    }

    // LN1 affine params (log2e-folded biases); latency hides under barrier
    float g1[4], gC[4], l2b1[4], l2bC[4];
    #pragma unroll
    for (int np = 0; np < 2; ++np)
        #pragma unroll
        for (int b = 0; b < 2; ++b) {
            int nt = np * 2 + b;
            int a = wc * 64 + np * 32 + b * 16 + l15;
            g1[nt] = ln1_g[a];       l2b1[nt] = ln1_b[a] * L2E;
            gC[nt] = ln1_g[256 + a]; l2bC[nt] = ln1_b[256 + a] * L2E;
        }
    __syncthreads();                                    // B2: sRed ready

    // ---- pass 2: stats fold + sigmoid*softplus; pads (l16==3) predicated out ----
    float rs[4], mr[4];
    #pragma unroll
    for (int j = 0; j < 4; ++j) {
        int row = l16 * 4 + j;
        float4 s4 = *reinterpret_cast<const float4*>(&sRed[0][row][0]);
        float4 q4 = *reinterpret_cast<const float4*>(&sRed[1][row][0]);
        float ssum = (s4.x + s4.y) + (s4.z + s4.w);
        float qsum = (q4.x + q4.y) + (q4.z + q4.w);
        float mu = ssum * (1.f / 512.f);
        float var = qsum * (1.f / 512.f) - mu * mu;
        float r = __builtin_amdgcn_rsqf(var + 1e-5f) * L2E;
        rs[j] = r; mr[j] = mu * r;
    }
    float pa[4];
    #pragma unroll
    for (int nt = 0; nt < 4; ++nt) {
        float tq = 0.f;
        #pragma unroll
        for (int j = 0; j < 4; ++j) {
            float ug = fmaf(fmaf(acc[nt][j],     rs[j], -mr[j]), g1[nt], l2b1[nt]);
            float uc = fmaf(fmaf(acc[nt + 4][j], rs[j], -mr[j]), gC[nt], l2bC[nt]);
            float gt  = __builtin_amdgcn_rcpf(1.f + fexp2(-ug));
            float sp2 = flog2(1.f + fexp2(uc));
            tq = fmaf(gt, sp2, tq);
        }
        pa[nt] = (l16 < 3) ? tq : 0.f;                  // pad rows excluded
        pa[nt] += __shfl_xor(pa[nt], 16, 64);           // sum 3 real l16 groups
        pa[nt] += __shfl_xor(pa[nt], 32, 64);
    }

    // ---- LN2 partials over this wave's 64 output cols (scale-invariant) ----
    {
        float s0 = (pa[0] + pa[1]) + (pa[2] + pa[3]);
        float q0 = fmaf(pa[0], pa[0], fmaf(pa[1], pa[1], fmaf(pa[2], pa[2], pa[3] * pa[3])));
        s0 = rowsum16(s0); q0 = rowsum16(q0);
        if (lane == 0) { sL2[0][wc] = s0; sL2[1][wc] = q0; }
    }
    __syncthreads();                                    // B3: sL2 ready

    // ---- LN2 + residual ----
    {
        float4 sv = *reinterpret_cast<const float4*>(&sL2[0][0]);
        float4 qv = *reinterpret_cast<const float4*>(&sL2[1][0]);
        float ssum = (sv.x + sv.y) + (sv.z + sv.w);
        float qsum = (qv.x + qv.y) + (qv.z + qv.w);
        float mu = ssum * (1.f / 256.f);
        float var = qsum * (1.f / 256.f) - mu * mu;
        float rstd = __builtin_amdgcn_rsqf(var + 1e-5f);
        if (l16 == 0) {
            #pragma unroll
            for (int np = 0; np < 2; ++np)
                #pragma unroll
                for (int b = 0; b < 2; ++b) {
                    int nt = np * 2 + b;
                    int c = wc * 64 + np * 32 + b * 16 + l15;
                    out[(size_t)gi * 256 + c] = atom[(size_t)gi * 256 + c]
                                              + (pa[nt] - mu) * rstd * ln2_g[c] + ln2_b[c];
                }
        }
    }
}

extern "C" void kernel_launch(void* const* d_in, const int* in_sizes, int n_in,
                              void* d_out, int out_size, void* d_ws, size_t ws_size,
                              hipStream_t stream) {
    const float* atom  = (const float*)d_in[0];
    const float* bond  = (const float*)d_in[1];
    const float* fc_w  = (const float*)d_in[2];
    const float* fc_b  = (const float*)d_in[3];
    const float* ln1_g = (const float*)d_in[4];
    const float* ln1_b = (const float*)d_in[5];
    const float* ln2_g = (const float*)d_in[6];
    const float* ln2_b = (const float*)d_in[7];
    const int*   nbr   = (const int*)d_in[8];

    char* ws = (char*)d_ws;
    unsigned short* P   = (unsigned short*)ws;                          // 61,440,000 B
    unsigned short* Wp1 = (unsigned short*)(ws + 61440000);             // 524,288 B
    unsigned short* Wp3 = (unsigned short*)(ws + 61440000 + 524288);    // 131,072 B
    float* outp = (float*)d_out;

    hipLaunchKernelGGL(pack_weights, dim3(1280), dim3(256), 0, stream, fc_w, Wp1, Wp3);
    hipLaunchKernelGGL(gemm_p, dim3(235, 2), dim3(512), 0, stream, atom, fc_b, Wp1, P);
    hipLaunchKernelGGL(fused_conv, dim3(30000), dim3(256), 0, stream,
                       atom, bond, nbr, P, Wp3, ln1_g, ln1_b, ln2_g, ln2_b, outp);
}